// Round 4
// baseline (605.489 us; speedup 1.0000x reference)
//
#include <hip/hip_runtime.h>

typedef unsigned short u16;
typedef unsigned int u32;
using short8 = __attribute__((ext_vector_type(8))) short;
using f32x4  = __attribute__((ext_vector_type(4))) float;

#define D_MODEL 1024
#define NHEAD 16
#define DKV 64
#define TSEQ 2048
#define BATCH 2
#define L2E 1.44269504f
#define CSHIFT 12.0f

// global -> LDS direct DMA, 16 B per lane. LDS dest must be wave-uniform
// base + lane*16 — our per-thread pointers satisfy that by construction.
#define GLOAD16(gp, lp)                                                      \
    __builtin_amdgcn_global_load_lds(                                        \
        (const __attribute__((address_space(1))) u32*)(gp),                  \
        (__attribute__((address_space(3))) u32*)(lp), 16, 0, 0)

__device__ __forceinline__ u16 f2bf(float f) {      // RNE
    union { float f; u32 i; } c; c.f = f;
    u32 x = c.i;
    return (u16)((x + 0x7FFFu + ((x >> 16) & 1u)) >> 16);
}
__device__ __forceinline__ u16 f2bf_fast(float f) { // round-half-up (P only)
    union { float f; u32 i; } c; c.f = f;
    return (u16)((c.i + 0x8000u) >> 16);
}

// ---------------------------------------------------------------------------
// Kernel 0: fp32 -> bf16 prep. Converts x (4.19M) + Wq/Wk/Wv/Wo (1.05M each)
// into ws, laid out contiguously: [xbf | wq | wk | wv | wo]. Exact coverage.
// ---------------------------------------------------------------------------
__global__ __launch_bounds__(256) void prep_cvt(
    const float* __restrict__ x,  const float* __restrict__ Wq,
    const float* __restrict__ Wk, const float* __restrict__ Wv,
    const float* __restrict__ Wo, u16* __restrict__ dst)
{
    size_t e = ((size_t)blockIdx.x * 256 + threadIdx.x) * 8;
    const float* src; size_t off;
    if (e < 4194304u)      { src = x;  off = e; }
    else if (e < 5242880u) { src = Wq; off = e - 4194304u; }
    else if (e < 6291456u) { src = Wk; off = e - 5242880u; }
    else if (e < 7340032u) { src = Wv; off = e - 6291456u; }
    else                   { src = Wo; off = e - 7340032u; }
    float4 a = *(const float4*)(src + off);
    float4 b = *(const float4*)(src + off + 4);
    short8 v;
    v[0] = (short)f2bf(a.x); v[1] = (short)f2bf(a.y);
    v[2] = (short)f2bf(a.z); v[3] = (short)f2bf(a.w);
    v[4] = (short)f2bf(b.x); v[5] = (short)f2bf(b.y);
    v[6] = (short)f2bf(b.z); v[7] = (short)f2bf(b.w);
    *(short8*)(dst + e) = v;
}

// ---------------------------------------------------------------------------
// Kernel 1: fused QKV projection, m97 structure: linear [128][64] LDS tiles
// filled by global_load_lds dwordx4 (no register round-trip). Grid = 768 1-D,
// XCD-swizzled.  (UNCHANGED this round.)
// ---------------------------------------------------------------------------
__global__ __launch_bounds__(256) void qkv_gemm(
    const u16* __restrict__ xbf, const u16* __restrict__ wbf,
    const float* __restrict__ bq, const float* __restrict__ bk,
    const float* __restrict__ bv, u16* __restrict__ qkv)
{
    __shared__ __align__(16) u16 Alds[128 * 64];
    __shared__ __align__(16) u16 Blds[128 * 64];

    const int fid = blockIdx.x;
    const int xcd = fid & 7, ii = fid >> 3;       // ii in 0..95
    const int z = ii >> 5, r2 = ii & 31;
    const int nb = r2 & 7, mb = xcd * 4 + (r2 >> 3);
    const int n0 = nb * 128, m0 = mb * 128;
    const u16* W = wbf + (size_t)z * 1048576;
    const float* bias = (z == 0) ? bq : (z == 1) ? bk : bv;
    u16* out = qkv + (size_t)z * 4194304;

    const int t = threadIdx.x;
    const int wave = t >> 6, lane = t & 63, l15 = lane & 15, quad = lane >> 4;
    const int wm = (wave >> 1) * 64, wn = (wave & 1) * 64;

    f32x4 acc[4][4];
#pragma unroll
    for (int i = 0; i < 4; ++i)
#pragma unroll
        for (int j = 0; j < 4; ++j)
#pragma unroll
            for (int r = 0; r < 4; ++r) acc[i][j][r] = 0.f;

    const int rs = t >> 3, cs = (t & 7) * 8;
    const u16* ga = xbf + (size_t)(m0 + rs) * 1024 + cs;
    const u16* gb = W   + (size_t)(n0 + rs) * 1024 + cs;
    u16* la = &Alds[rs * 64 + cs];
    u16* lb = &Blds[rs * 64 + cs];

    for (int kt = 0; kt < 16; ++kt) {
        const int k0 = kt * 64;
#pragma unroll
        for (int c = 0; c < 4; ++c) {
            GLOAD16(ga + (size_t)(c * 32) * 1024 + k0, la + c * 32 * 64);
            GLOAD16(gb + (size_t)(c * 32) * 1024 + k0, lb + c * 32 * 64);
        }
        __syncthreads();   // compiler drains vmcnt(0) before s_barrier
#pragma unroll
        for (int ki = 0; ki < 2; ++ki) {
            short8 af[4], bfr[4];
#pragma unroll
            for (int i = 0; i < 4; ++i)
                af[i] = *(const short8*)&Alds[(wm + i * 16 + l15) * 64 + ki * 32 + quad * 8];
#pragma unroll
            for (int j = 0; j < 4; ++j)
                bfr[j] = *(const short8*)&Blds[(wn + j * 16 + l15) * 64 + ki * 32 + quad * 8];
#pragma unroll
            for (int i = 0; i < 4; ++i)
#pragma unroll
                for (int j = 0; j < 4; ++j)
                    acc[i][j] = __builtin_amdgcn_mfma_f32_16x16x32_bf16(af[i], bfr[j], acc[i][j], 0, 0, 0);
        }
        __syncthreads();
    }

#pragma unroll
    for (int j = 0; j < 4; ++j) {
        int n = n0 + wn + j * 16 + l15;
        float bb = bias[n];
        int h = n >> 6, d = n & 63;
#pragma unroll
        for (int i = 0; i < 4; ++i)
#pragma unroll
            for (int r = 0; r < 4; ++r) {
                int m = m0 + wm + i * 16 + quad * 4 + r;
                int bidx = m >> 11, tt = m & 2047;
                out[(((size_t)(bidx * NHEAD + h)) * TSEQ + tt) * DKV + d] =
                    f2bf(acc[i][j][r] + bb);
            }
    }
}

// ---------------------------------------------------------------------------
// Kernel 2: flash attention, batch-merged 512-thread blocks. RESTRUCTURED:
//  - ONE barrier per tile (was 2). P is wave-private (each wave writes/reads
//    only its own 16 Plds rows), so the P-write->PV barrier was never needed;
//    same-wave DS ordering + compiler lgkmcnt waits suffice.
//  - K double-buffered, prefetched via global_load_lds for tile kt+1 at the
//    TOP of iteration kt -> loads land under the whole compute phase (T3).
//  - V T14 async-split: global->reg loads for kt+1 at iteration top,
//    ds_writes AFTER compute, before the single barrier.
//  - Vt stride 72->64 (XOR-chunk swizzle carries conflict-avoidance: writes
//    2-way/free, reads uniform 8 lanes/chunk). Plds 72->64 with chunk-XOR
//    swizzle (phys = chunk ^ (row&7)), write 2-way/free.
//  LDS = K 32K + Vt 32K + P 16K = 80 KB exactly -> 2 blocks/CU, 16 waves/CU.
// Fixed-shift softmax (exact). Bias global->reg, shared across batch groups.
// ---------------------------------------------------------------------------
__global__ __launch_bounds__(512, 4) void attn_kernel(
    const u16* __restrict__ qws, const u16* __restrict__ kws, const u16* __restrict__ vws,
    const float* __restrict__ bias, u16* __restrict__ ows)
{
    __shared__ __align__(16) u16 Klds[2][2][64 * 64];   // [bg][buf]
    __shared__ __align__(16) u16 Vt[2][2][64 * 64];     // [bg][buf]
    __shared__ __align__(16) u16 Plds[2][64 * 64];      // [bg], wave-private rows

    const int fid = blockIdx.x;
    const int xcd = fid & 7, ii = fid >> 3;        // ii in 0..63
    const int h = xcd * 2 + (ii >> 5);             // 2 heads per XCD
    const int qt = ii & 31;
    const int q0 = qt * 64;

    const int t = threadIdx.x;
    const int bg = t >> 8;                         // batch group 0/1
    const int tl = t & 255;
    const int wave = tl >> 6, lane = tl & 63, l15 = lane & 15, quad = lane >> 4;
    const int bh = bg * NHEAD + h;
    const size_t bhoff = (size_t)bh * TSEQ * DKV;

    // Q A-fragments, loop-invariant in registers
    short8 qa0, qa1;
    {
        const u16* qp = qws + bhoff + (size_t)(q0 + wave * 16 + l15) * DKV;
        qa0 = *(const short8*)(qp + quad * 8);
        qa1 = *(const short8*)(qp + 32 + quad * 8);
    }

    float l_run[4] = {0.f, 0.f, 0.f, 0.f};
    f32x4 o_acc[4];
#pragma unroll
    for (int db = 0; db < 4; ++db)
#pragma unroll
        for (int r = 0; r < 4; ++r) o_acc[db][r] = 0.f;

    const float* bias_h = bias + ((size_t)h * TSEQ + q0) * TSEQ;
    const int a8 = tl & 7, c8 = a8 * 8, rp = tl >> 3;
    const int rbase = wave * 16 + quad * 4;
    const int sw8 = l15 & 7;                       // K/P read swizzle
    const int vbk = rp >> 2;                       // V k-pair chunk (0..7)
    const int vsl = 2 * (rp & 3);                  // u16 offset of u32 slot

    // staging pointers (loop-invariant). K source pre-swizzled per row:
    // lds[row][c] holds K[row][(c ^ (row&7))*8..]
    const u16* kpbase = kws + bhoff + (size_t)rp * DKV + ((a8 ^ (rp & 7)) * 8);
    const u16* vpbase = vws + bhoff + (size_t)(2 * rp) * DKV + c8;
    u16* klA = &Klds[bg][0][rp * 64 + c8];
    u16* klB = &Klds[bg][1][rp * 64 + c8];

    // --- prologue: stage tile 0 into buf 0 ---
    {
        GLOAD16(kpbase, klA);
        GLOAD16(kpbase + 32 * DKV, klA + 32 * 64);
        short8 v0 = *(const short8*)vpbase;
        short8 v1 = *(const short8*)(vpbase + DKV);
        u16* vtb = &Vt[bg][0][0];
#pragma unroll
        for (int j = 0; j < 8; ++j) {
            int d = c8 + j;
            u32 val = ((u32)(u16)v0[j]) | (((u32)(u16)v1[j]) << 16);
            *(u32*)&vtb[d * 64 + ((vbk ^ a8) * 8) + vsl] = val;
        }
    }
    __syncthreads();

    for (int kt = 0; kt < TSEQ / 64; ++kt) {
        const int kc0 = kt * 64;
        const int cur = kt & 1;

        // [A] prefetch tile kt+1 (clamped; last-iter prefetch is harmless,
        // written to the never-again-read buffer). K -> LDS direct; V -> regs.
        const size_t koff = (size_t)((kt < 31) ? kc0 + 64 : kc0) * DKV;
        {
            u16* kl = cur ? klA : klB;
            GLOAD16(kpbase + koff, kl);
            GLOAD16(kpbase + koff + 32 * DKV, kl + 32 * 64);
        }
        short8 v0n = *(const short8*)(vpbase + koff);
        short8 v1n = *(const short8*)(vpbase + koff + DKV);

        // bias tile kt -> registers (C-layout); both batch groups read the
        // same addresses -> group 1 hits cache. Covered by QK^T latency.
        float bz[16];
#pragma unroll
        for (int cb = 0; cb < 4; ++cb)
#pragma unroll
            for (int r = 0; r < 4; ++r)
                bz[cb * 4 + r] =
                    bias_h[(size_t)(rbase + r) * TSEQ + kc0 + cb * 16 + l15];

        // [B] S = Q K^T  (K frags via swizzled chunks from buf cur)
        f32x4 s[4];
#pragma unroll
        for (int cb = 0; cb < 4; ++cb)
#pragma unroll
            for (int r = 0; r < 4; ++r) s[cb][r] = 0.f;
#pragma unroll
        for (int cb = 0; cb < 4; ++cb) {
            const u16* kr = &Klds[bg][cur][(cb * 16 + l15) * 64];
            short8 kb0 = *(const short8*)(kr + ((quad ^ sw8) * 8));
            short8 kb1 = *(const short8*)(kr + (((quad + 4) ^ sw8) * 8));
            s[cb] = __builtin_amdgcn_mfma_f32_16x16x32_bf16(qa0, kb0, s[cb], 0, 0, 0);
            s[cb] = __builtin_amdgcn_mfma_f32_16x16x32_bf16(qa1, kb1, s[cb], 0, 0, 0);
        }

        // p = exp(s/8 + bias - C) via exp2; accumulate l; pack P to LDS
        // (swizzled: phys chunk = logical ^ (row&7); wave-private rows)
#pragma unroll
        for (int cb = 0; cb < 4; ++cb)
#pragma unroll
            for (int r = 0; r < 4; ++r) {
                float arg = fmaf(s[cb][r], 0.125f * L2E,
                                 fmaf(bz[cb * 4 + r], L2E, -CSHIFT * L2E));
                float p = exp2f(arg);
                l_run[r] += p;
                int row = rbase + r;
                int chunk = cb * 2 + (l15 >> 3);
                Plds[bg][row * 64 + ((chunk ^ (row & 7)) * 8) + (l15 & 7)] =
                    f2bf_fast(p);
            }

        // PV: O += P V  (same-wave P readback: lgkmcnt ordering, no barrier)
        {
            const int prow = wave * 16 + l15;
            const u16* prb = &Plds[bg][prow * 64];
            short8 pa0 = *(const short8*)(prb + ((quad ^ sw8) * 8));
            short8 pa1 = *(const short8*)(prb + (((quad + 4) ^ sw8) * 8));
            const u16* vtc = &Vt[bg][cur][0];
#pragma unroll
            for (int db = 0; db < 4; ++db) {
                int d = db * 16 + l15;
                int sw = (d >> 3) & 7;
                const u16* vr = &vtc[d * 64];
                short8 vb0 = *(const short8*)(vr + ((quad ^ sw) * 8));
                short8 vb1 = *(const short8*)(vr + (((4 + quad) ^ sw) * 8));
                o_acc[db] = __builtin_amdgcn_mfma_f32_16x16x32_bf16(pa0, vb0, o_acc[db], 0, 0, 0);
                o_acc[db] = __builtin_amdgcn_mfma_f32_16x16x32_bf16(pa1, vb1, o_acc[db], 0, 0, 0);
            }
        }

        // [C] V ds_write for tile kt+1 into buf cur^1 (T14 write-late)
        {
            u16* vtb = &Vt[bg][cur ^ 1][0];
#pragma unroll
            for (int j = 0; j < 8; ++j) {
                int d = c8 + j;
                u32 val = ((u32)(u16)v0n[j]) | (((u32)(u16)v1n[j]) << 16);
                *(u32*)&vtb[d * 64 + ((vbk ^ a8) * 8) + vsl] = val;
            }
        }
        __syncthreads();   // single barrier: drains vmcnt (K) + lgkmcnt (V)
    }

    // one-time l reduction across the 16-lane row group
#pragma unroll
    for (int r = 0; r < 4; ++r) {
        float v = l_run[r];
        v += __shfl_xor(v, 1);
        v += __shfl_xor(v, 2);
        v += __shfl_xor(v, 4);
        v += __shfl_xor(v, 8);
        l_run[r] = v;
    }
#pragma unroll
    for (int r = 0; r < 4; ++r) {
        float inv = 1.f / l_run[r];
        int row = q0 + rbase + r;
#pragma unroll
        for (int db = 0; db < 4; ++db)
            ows[bhoff + (size_t)row * DKV + db * 16 + l15] = f2bf(o_acc[db][r] * inv);
    }
}

// ---------------------------------------------------------------------------
// Kernel 3: output projection, 128x64 tiles -> grid 512 = 2 blocks/CU.
// m97 staging via global_load_lds, linear LDS. XCD-swizzled.
// (UNCHANGED this round.)
// ---------------------------------------------------------------------------
__global__ __launch_bounds__(256) void out_gemm(
    const u16* __restrict__ ows, const u16* __restrict__ wobf,
    const float* __restrict__ bo, float* __restrict__ out)
{
    __shared__ __align__(16) u16 Alds[128 * 64];
    __shared__ __align__(16) u16 Blds[64 * 64];

    const int fid = blockIdx.x;
    const int xcd = fid & 7, ii = fid >> 3;     // ii in 0..63
    const int nb = ii & 15, mb = xcd * 4 + (ii >> 4);
    const int n0 = nb * 64, m0 = mb * 128;

    const int t = threadIdx.x;
    const int wave = t >> 6, lane = t & 63, l15 = lane & 15, quad = lane >> 4;
    const int wm = (wave >> 1) * 64, wn = (wave & 1) * 32;   // wave tile 64x32

    f32x4 acc[4][2];
#pragma unroll
    for (int i = 0; i < 4; ++i)
#pragma unroll
        for (int j = 0; j < 2; ++j)
#pragma unroll
            for (int r = 0; r < 4; ++r) acc[i][j][r] = 0.f;

    const int rs = t >> 3, cs = (t & 7) * 8;
    const int bidx = m0 >> 11, tt0 = m0 & 2047;    // 128-row tile never crosses batch
    const u16* gaBase = ows + (((size_t)(bidx * NHEAD)) * TSEQ + tt0 + rs) * DKV + cs;
    const u16* gb = wobf + (size_t)(n0 + rs) * 1024 + cs;
    u16* la = &Alds[rs * 64 + cs];
    u16* lb = &Blds[rs * 64 + cs];

    for (int kt = 0; kt < 16; ++kt) {
        const int k0 = kt * 64;
#pragma unroll
        for (int c = 0; c < 4; ++c)
            GLOAD16(gaBase + ((size_t)kt * TSEQ + c * 32) * DKV, la + c * 32 * 64);
#pragma unroll
        for (int c = 0; c < 2; ++c)
            GLOAD16(gb + (size_t)(c * 32) * 1024 + k0, lb + c * 32 * 64);
        __syncthreads();
#pragma unroll
        for (int ki = 0; ki < 2; ++ki) {
            short8 af[4], bfr[2];
#pragma unroll
            for (int i = 0; i < 4; ++i)
                af[i] = *(const short8*)&Alds[(wm + i * 16 + l15) * 64 + ki * 32 + quad * 8];
#pragma unroll
            for (int j = 0; j < 2; ++j)
                bfr[j] = *(const short8*)&Blds[(wn + j * 16 + l15) * 64 + ki * 32 + quad * 8];
#pragma unroll
            for (int i = 0; i < 4; ++i)
#pragma unroll
                for (int j = 0; j < 2; ++j)
                    acc[i][j] = __builtin_amdgcn_mfma_f32_16x16x32_bf16(af[i], bfr[j], acc[i][j], 0, 0, 0);
        }
        __syncthreads();
    }

#pragma unroll
    for (int j = 0; j < 2; ++j) {
        int n = n0 + wn + j * 16 + l15;
        float bb = bo[n];
#pragma unroll
        for (int i = 0; i < 4; ++i)
#pragma unroll
            for (int r = 0; r < 4; ++r) {
                int m = m0 + wm + i * 16 + quad * 4 + r;
                out[(size_t)m * 1024 + n] = acc[i][j][r] + bb;
            }
    }
}

extern "C" void kernel_launch(void* const* d_in, const int* in_sizes, int n_in,
                              void* d_out, int out_size, void* d_ws, size_t ws_size,
                              hipStream_t stream)
{
    const float* x  = (const float*)d_in[0];
    const float* ab = (const float*)d_in[1];
    const float* Wq = (const float*)d_in[2];
    const float* bq = (const float*)d_in[3];
    const float* Wk = (const float*)d_in[4];
    const float* bk = (const float*)d_in[5];
    const float* Wv = (const float*)d_in[6];
    const float* bv = (const float*)d_in[7];
    const float* Wo = (const float*)d_in[8];
    const float* bo = (const float*)d_in[9];
    float* out = (float*)d_out;

    u16* wsu = (u16*)d_ws;
    // ws layout (u16 elems): [0 xbf 4.19M | 4.19M wq,wk,wv,wo 4x1.05M |
    //                         8.39M q,k,v 3x4.19M | 20.97M o 4.19M]  = 48 MB
    const size_t WBF = 4194304;
    const size_t QKV = 8388608;
    const size_t OWS = 20971520;
    const size_t QSZ = 4194304;

    prep_cvt<<<4096, 256, 0, stream>>>(x, Wq, Wk, Wv, Wo, wsu);
    qkv_gemm<<<768, 256, 0, stream>>>(wsu, wsu + WBF, bq, bk, bv, wsu + QKV);
    attn_kernel<<<512, 512, 0, stream>>>(wsu + QKV, wsu + QKV + QSZ,
                                         wsu + QKV + 2 * QSZ, ab, wsu + OWS);
    out_gemm<<<512, 256, 0, stream>>>(wsu + OWS, wsu + WBF + 3 * 1048576, bo, out);
}

// Round 5
// 505.508 us; speedup vs baseline: 1.1978x; 1.1978x over previous
//
#include <hip/hip_runtime.h>

typedef unsigned short u16;
typedef unsigned int u32;
using short8 = __attribute__((ext_vector_type(8))) short;
using f32x4  = __attribute__((ext_vector_type(4))) float;

#define D_MODEL 1024
#define NHEAD 16
#define DKV 64
#define TSEQ 2048
#define BATCH 2
#define L2E 1.44269504f
#define CSHIFT 12.0f

// global -> LDS direct DMA, 16 B per lane. LDS dest must be wave-uniform
// base + lane*16 — our per-thread pointers satisfy that by construction.
#define GLOAD16(gp, lp)                                                      \
    __builtin_amdgcn_global_load_lds(                                        \
        (const __attribute__((address_space(1))) u32*)(gp),                  \
        (__attribute__((address_space(3))) u32*)(lp), 16, 0, 0)

__device__ __forceinline__ u16 f2bf(float f) {      // RNE
    union { float f; u32 i; } c; c.f = f;
    u32 x = c.i;
    return (u16)((x + 0x7FFFu + ((x >> 16) & 1u)) >> 16);
}
__device__ __forceinline__ u16 f2bf_fast(float f) { // round-half-up (P only)
    union { float f; u32 i; } c; c.f = f;
    return (u16)((c.i + 0x8000u) >> 16);
}

// ---------------------------------------------------------------------------
// Kernel 0: fp32 -> bf16 prep. (UNCHANGED)
// ---------------------------------------------------------------------------
__global__ __launch_bounds__(256) void prep_cvt(
    const float* __restrict__ x,  const float* __restrict__ Wq,
    const float* __restrict__ Wk, const float* __restrict__ Wv,
    const float* __restrict__ Wo, u16* __restrict__ dst)
{
    size_t e = ((size_t)blockIdx.x * 256 + threadIdx.x) * 8;
    const float* src; size_t off;
    if (e < 4194304u)      { src = x;  off = e; }
    else if (e < 5242880u) { src = Wq; off = e - 4194304u; }
    else if (e < 6291456u) { src = Wk; off = e - 5242880u; }
    else if (e < 7340032u) { src = Wv; off = e - 6291456u; }
    else                   { src = Wo; off = e - 7340032u; }
    float4 a = *(const float4*)(src + off);
    float4 b = *(const float4*)(src + off + 4);
    short8 v;
    v[0] = (short)f2bf(a.x); v[1] = (short)f2bf(a.y);
    v[2] = (short)f2bf(a.z); v[3] = (short)f2bf(a.w);
    v[4] = (short)f2bf(b.x); v[5] = (short)f2bf(b.y);
    v[6] = (short)f2bf(b.z); v[7] = (short)f2bf(b.w);
    *(short8*)(dst + e) = v;
}

// ---------------------------------------------------------------------------
// Kernel 1: fused QKV projection, m97 structure. (UNCHANGED)
// ---------------------------------------------------------------------------
__global__ __launch_bounds__(256) void qkv_gemm(
    const u16* __restrict__ xbf, const u16* __restrict__ wbf,
    const float* __restrict__ bq, const float* __restrict__ bk,
    const float* __restrict__ bv, u16* __restrict__ qkv)
{
    __shared__ __align__(16) u16 Alds[128 * 64];
    __shared__ __align__(16) u16 Blds[128 * 64];

    const int fid = blockIdx.x;
    const int xcd = fid & 7, ii = fid >> 3;       // ii in 0..95
    const int z = ii >> 5, r2 = ii & 31;
    const int nb = r2 & 7, mb = xcd * 4 + (r2 >> 3);
    const int n0 = nb * 128, m0 = mb * 128;
    const u16* W = wbf + (size_t)z * 1048576;
    const float* bias = (z == 0) ? bq : (z == 1) ? bk : bv;
    u16* out = qkv + (size_t)z * 4194304;

    const int t = threadIdx.x;
    const int wave = t >> 6, lane = t & 63, l15 = lane & 15, quad = lane >> 4;
    const int wm = (wave >> 1) * 64, wn = (wave & 1) * 64;

    f32x4 acc[4][4];
#pragma unroll
    for (int i = 0; i < 4; ++i)
#pragma unroll
        for (int j = 0; j < 4; ++j)
#pragma unroll
            for (int r = 0; r < 4; ++r) acc[i][j][r] = 0.f;

    const int rs = t >> 3, cs = (t & 7) * 8;
    const u16* ga = xbf + (size_t)(m0 + rs) * 1024 + cs;
    const u16* gb = W   + (size_t)(n0 + rs) * 1024 + cs;
    u16* la = &Alds[rs * 64 + cs];
    u16* lb = &Blds[rs * 64 + cs];

    for (int kt = 0; kt < 16; ++kt) {
        const int k0 = kt * 64;
#pragma unroll
        for (int c = 0; c < 4; ++c) {
            GLOAD16(ga + (size_t)(c * 32) * 1024 + k0, la + c * 32 * 64);
            GLOAD16(gb + (size_t)(c * 32) * 1024 + k0, lb + c * 32 * 64);
        }
        __syncthreads();
#pragma unroll
        for (int ki = 0; ki < 2; ++ki) {
            short8 af[4], bfr[4];
#pragma unroll
            for (int i = 0; i < 4; ++i)
                af[i] = *(const short8*)&Alds[(wm + i * 16 + l15) * 64 + ki * 32 + quad * 8];
#pragma unroll
            for (int j = 0; j < 4; ++j)
                bfr[j] = *(const short8*)&Blds[(wn + j * 16 + l15) * 64 + ki * 32 + quad * 8];
#pragma unroll
            for (int i = 0; i < 4; ++i)
#pragma unroll
                for (int j = 0; j < 4; ++j)
                    acc[i][j] = __builtin_amdgcn_mfma_f32_16x16x32_bf16(af[i], bfr[j], acc[i][j], 0, 0, 0);
        }
        __syncthreads();
    }

#pragma unroll
    for (int j = 0; j < 4; ++j) {
        int n = n0 + wn + j * 16 + l15;
        float bb = bias[n];
        int h = n >> 6, d = n & 63;
#pragma unroll
        for (int i = 0; i < 4; ++i)
#pragma unroll
            for (int r = 0; r < 4; ++r) {
                int m = m0 + wm + i * 16 + quad * 4 + r;
                int bidx = m >> 11, tt = m & 2047;
                out[(((size_t)(bidx * NHEAD + h)) * TSEQ + tt) * DKV + d] =
                    f2bf(acc[i][j][r] + bb);
            }
    }
}

// ---------------------------------------------------------------------------
// Kernel 2: flash attention, batch-merged 512-thread blocks.
// ROUND-3 LDS LAYOUTS RESTORED (Vt/Plds stride 72: conflict-light; the r4
// stride-64 repack put rows at 128B stride -> row dropped out of the bank
// index -> real multi-way conflicts). NEW SCHEDULE keeps r4's good idea:
//   A) QK^T on Klds (staged last iter)
//   B) barrier #1: Klds free to overwrite (no VMEM outstanding -> cheap)
//   C) issue ALL next-tile loads: K via global_load_lds (single K buffer,
//      legal after B), V -> regs, bias(kt+1) -> regs (one tile ahead)
//   D) softmax on s with bias(kt) from regs; P -> LDS (wave-private rows)
//   E) PV from own P rows (same-wave lgkm ordering, NO barrier needed)
//      + Vt[cur] (double-buffered)
//   F) V ds_writes into Vt[cur^1]
//   G) barrier #2: drains C's loads -- covered by D+E+F compute (~400 cyc)
// vs round 3 where the staging barrier drained K/V/bias latency with zero
// compute overlap every tile. Barrier count unchanged (2/tile).
// Fixed-shift softmax (exact: constant shift cancels).
// LDS = K 16K + Vt 36K + P 18K = 70 KB -> 2 blocks/CU, 16 waves/CU.
// ---------------------------------------------------------------------------
__global__ __launch_bounds__(512, 4) void attn_kernel(
    const u16* __restrict__ qws, const u16* __restrict__ kws, const u16* __restrict__ vws,
    const float* __restrict__ bias, u16* __restrict__ ows)
{
    __shared__ __align__(16) u16 Klds[2][64 * 64];      // [bg], single-buffered
    __shared__ __align__(16) u16 Vt[2][2][64 * 72];     // [bg][buf]
    __shared__ __align__(16) u16 Plds[2][64 * 72];      // [bg], wave-private rows

    const int fid = blockIdx.x;
    const int xcd = fid & 7, ii = fid >> 3;        // ii in 0..63
    const int h = xcd * 2 + (ii >> 5);             // 2 heads per XCD
    const int qt = ii & 31;
    const int q0 = qt * 64;

    const int t = threadIdx.x;
    const int bg = t >> 8;                         // batch group 0/1
    const int tl = t & 255;
    const int wave = tl >> 6, lane = tl & 63, l15 = lane & 15, quad = lane >> 4;
    const int bh = bg * NHEAD + h;
    const size_t bhoff = (size_t)bh * TSEQ * DKV;

    // Q A-fragments, loop-invariant in registers
    short8 qa0, qa1;
    {
        const u16* qp = qws + bhoff + (size_t)(q0 + wave * 16 + l15) * DKV;
        qa0 = *(const short8*)(qp + quad * 8);
        qa1 = *(const short8*)(qp + 32 + quad * 8);
    }

    float l_run[4] = {0.f, 0.f, 0.f, 0.f};
    f32x4 o_acc[4];
#pragma unroll
    for (int db = 0; db < 4; ++db)
#pragma unroll
        for (int r = 0; r < 4; ++r) o_acc[db][r] = 0.f;

    const float* bias_h = bias + ((size_t)h * TSEQ + q0) * TSEQ;
    const int a8 = tl & 7, c8 = a8 * 8, rp = tl >> 3;
    const int rbase = wave * 16 + quad * 4;
    const int sw8 = l15 & 7;                       // K read swizzle
    const int vbk = rp >> 2;                       // V logical k-chunk
    const int vkcl = (2 * rp) & 7;                 // u16 slot of packed pair

    // staging pointers (loop-invariant). K source pre-swizzled per row:
    // lds[row][c] holds K[row][(c ^ (row&7))*8..]; dest is lane-linear.
    const u16* kpbase = kws + bhoff + (size_t)rp * DKV + ((a8 ^ (rp & 7)) * 8);
    const u16* vpbase = vws + bhoff + (size_t)(2 * rp) * DKV + c8;
    u16* kl = &Klds[bg][rp * 64 + c8];

    // --- prologue: stage K[0], V[0]; load bias[0] into regs ---
    GLOAD16(kpbase, kl);
    GLOAD16(kpbase + 32 * DKV, kl + 32 * 64);
    {
        short8 v0 = *(const short8*)vpbase;
        short8 v1 = *(const short8*)(vpbase + DKV);
        u16* vtb = &Vt[bg][0][0];
#pragma unroll
        for (int j = 0; j < 8; ++j) {
            int d = c8 + j;
            u32 val = ((u32)(u16)v0[j]) | (((u32)(u16)v1[j]) << 16);
            *(u32*)&vtb[d * 72 + ((vbk ^ a8) * 8) + vkcl] = val;
        }
    }
    float bz[16];
#pragma unroll
    for (int cb = 0; cb < 4; ++cb)
#pragma unroll
        for (int r = 0; r < 4; ++r)
            bz[cb * 4 + r] = bias_h[(size_t)(rbase + r) * TSEQ + cb * 16 + l15];
    __syncthreads();   // drains prologue staging

    for (int kt = 0; kt < TSEQ / 64; ++kt) {
        const int cur = kt & 1;

        // [A] S = Q K^T from Klds (swizzled chunks)
        f32x4 s[4];
#pragma unroll
        for (int cb = 0; cb < 4; ++cb)
#pragma unroll
            for (int r = 0; r < 4; ++r) s[cb][r] = 0.f;
#pragma unroll
        for (int cb = 0; cb < 4; ++cb) {
            const u16* kr = &Klds[bg][(cb * 16 + l15) * 64];
            short8 kb0 = *(const short8*)(kr + ((quad ^ sw8) * 8));
            short8 kb1 = *(const short8*)(kr + (((quad + 4) ^ sw8) * 8));
            s[cb] = __builtin_amdgcn_mfma_f32_16x16x32_bf16(qa0, kb0, s[cb], 0, 0, 0);
            s[cb] = __builtin_amdgcn_mfma_f32_16x16x32_bf16(qa1, kb1, s[cb], 0, 0, 0);
        }

        // [B] barrier #1: everyone done reading Klds; nothing in flight
        __syncthreads();

        // [C] issue next-tile loads (clamped at the last tile; the redundant
        // re-stage is harmless). Drained at [G], covered by D+E+F compute.
        const int ktn = (kt < 31) ? kt + 1 : kt;
        const size_t koff = (size_t)ktn * 64 * DKV;
        GLOAD16(kpbase + koff, kl);
        GLOAD16(kpbase + koff + 32 * DKV, kl + 32 * 64);
        short8 v0n = *(const short8*)(vpbase + koff);
        short8 v1n = *(const short8*)(vpbase + koff + DKV);
        float bzn[16];
#pragma unroll
        for (int cb = 0; cb < 4; ++cb)
#pragma unroll
            for (int r = 0; r < 4; ++r)
                bzn[cb * 4 + r] =
                    bias_h[(size_t)(rbase + r) * TSEQ + ktn * 64 + cb * 16 + l15];

        // [D] p = exp2(s/8*log2e + bias*log2e - C*log2e); l += p; P -> LDS
#pragma unroll
        for (int cb = 0; cb < 4; ++cb)
#pragma unroll
            for (int r = 0; r < 4; ++r) {
                float arg = fmaf(s[cb][r], 0.125f * L2E,
                                 fmaf(bz[cb * 4 + r], L2E, -CSHIFT * L2E));
                float p = exp2f(arg);
                l_run[r] += p;
                Plds[bg][(rbase + r) * 72 + cb * 16 + l15] = f2bf_fast(p);
            }

        // [E] PV: O += P V  (own P rows: same-wave DS ordering, no barrier)
        {
            const u16* pr = &Plds[bg][(wave * 16 + l15) * 72 + quad * 8];
            short8 pa0 = *(const short8*)pr;
            short8 pa1 = *(const short8*)(pr + 32);
            const u16* vtc = &Vt[bg][cur][0];
#pragma unroll
            for (int db = 0; db < 4; ++db) {
                int d = db * 16 + l15;
                int sw = (d >> 3) & 7;
                const u16* vr = &vtc[d * 72];
                short8 vb0 = *(const short8*)(vr + ((quad ^ sw) * 8));
                short8 vb1 = *(const short8*)(vr + (((4 + quad) ^ sw) * 8));
                o_acc[db] = __builtin_amdgcn_mfma_f32_16x16x32_bf16(pa0, vb0, o_acc[db], 0, 0, 0);
                o_acc[db] = __builtin_amdgcn_mfma_f32_16x16x32_bf16(pa1, vb1, o_acc[db], 0, 0, 0);
            }
        }

        // [F] V ds_write for tile kt+1 into Vt[cur^1]
        {
            u16* vtb = &Vt[bg][cur ^ 1][0];
#pragma unroll
            for (int j = 0; j < 8; ++j) {
                int d = c8 + j;
                u32 val = ((u32)(u16)v0n[j]) | (((u32)(u16)v1n[j]) << 16);
                *(u32*)&vtb[d * 72 + ((vbk ^ a8) * 8) + vkcl] = val;
            }
        }
#pragma unroll
        for (int i = 0; i < 16; ++i) bz[i] = bzn[i];

        // [G] barrier #2: drains K global_load_lds (vmcnt) + V writes (lgkm)
        __syncthreads();
    }

    // one-time l reduction across the 16-lane row group
#pragma unroll
    for (int r = 0; r < 4; ++r) {
        float v = l_run[r];
        v += __shfl_xor(v, 1);
        v += __shfl_xor(v, 2);
        v += __shfl_xor(v, 4);
        v += __shfl_xor(v, 8);
        l_run[r] = v;
    }
#pragma unroll
    for (int r = 0; r < 4; ++r) {
        float inv = 1.f / l_run[r];
        int row = q0 + rbase + r;
#pragma unroll
        for (int db = 0; db < 4; ++db)
            ows[bhoff + (size_t)row * DKV + db * 16 + l15] = f2bf(o_acc[db][r] * inv);
    }
}

// ---------------------------------------------------------------------------
// Kernel 3: output projection, 128x64 tiles -> grid 512 = 2 blocks/CU.
// (UNCHANGED)
// ---------------------------------------------------------------------------
__global__ __launch_bounds__(256) void out_gemm(
    const u16* __restrict__ ows, const u16* __restrict__ wobf,
    const float* __restrict__ bo, float* __restrict__ out)
{
    __shared__ __align__(16) u16 Alds[128 * 64];
    __shared__ __align__(16) u16 Blds[64 * 64];

    const int fid = blockIdx.x;
    const int xcd = fid & 7, ii = fid >> 3;     // ii in 0..63
    const int nb = ii & 15, mb = xcd * 4 + (ii >> 4);
    const int n0 = nb * 64, m0 = mb * 128;

    const int t = threadIdx.x;
    const int wave = t >> 6, lane = t & 63, l15 = lane & 15, quad = lane >> 4;
    const int wm = (wave >> 1) * 64, wn = (wave & 1) * 32;   // wave tile 64x32

    f32x4 acc[4][2];
#pragma unroll
    for (int i = 0; i < 4; ++i)
#pragma unroll
        for (int j = 0; j < 2; ++j)
#pragma unroll
            for (int r = 0; r < 4; ++r) acc[i][j][r] = 0.f;

    const int rs = t >> 3, cs = (t & 7) * 8;
    const int bidx = m0 >> 11, tt0 = m0 & 2047;    // 128-row tile never crosses batch
    const u16* gaBase = ows + (((size_t)(bidx * NHEAD)) * TSEQ + tt0 + rs) * DKV + cs;
    const u16* gb = wobf + (size_t)(n0 + rs) * 1024 + cs;
    u16* la = &Alds[rs * 64 + cs];
    u16* lb = &Blds[rs * 64 + cs];

    for (int kt = 0; kt < 16; ++kt) {
        const int k0 = kt * 64;
#pragma unroll
        for (int c = 0; c < 4; ++c)
            GLOAD16(gaBase + ((size_t)kt * TSEQ + c * 32) * DKV, la + c * 32 * 64);
#pragma unroll
        for (int c = 0; c < 2; ++c)
            GLOAD16(gb + (size_t)(c * 32) * 1024 + k0, lb + c * 32 * 64);
        __syncthreads();
#pragma unroll
        for (int ki = 0; ki < 2; ++ki) {
            short8 af[4], bfr[2];
#pragma unroll
            for (int i = 0; i < 4; ++i)
                af[i] = *(const short8*)&Alds[(wm + i * 16 + l15) * 64 + ki * 32 + quad * 8];
#pragma unroll
            for (int j = 0; j < 2; ++j)
                bfr[j] = *(const short8*)&Blds[(wn + j * 16 + l15) * 64 + ki * 32 + quad * 8];
#pragma unroll
            for (int i = 0; i < 4; ++i)
#pragma unroll
                for (int j = 0; j < 2; ++j)
                    acc[i][j] = __builtin_amdgcn_mfma_f32_16x16x32_bf16(af[i], bfr[j], acc[i][j], 0, 0, 0);
        }
        __syncthreads();
    }

#pragma unroll
    for (int j = 0; j < 2; ++j) {
        int n = n0 + wn + j * 16 + l15;
        float bb = bo[n];
#pragma unroll
        for (int i = 0; i < 4; ++i)
#pragma unroll
            for (int r = 0; r < 4; ++r) {
                int m = m0 + wm + i * 16 + quad * 4 + r;
                out[(size_t)m * 1024 + n] = acc[i][j][r] + bb;
            }
    }
}

extern "C" void kernel_launch(void* const* d_in, const int* in_sizes, int n_in,
                              void* d_out, int out_size, void* d_ws, size_t ws_size,
                              hipStream_t stream)
{
    const float* x  = (const float*)d_in[0];
    const float* ab = (const float*)d_in[1];
    const float* Wq = (const float*)d_in[2];
    const float* bq = (const float*)d_in[3];
    const float* Wk = (const float*)d_in[4];
    const float* bk = (const float*)d_in[5];
    const float* Wv = (const float*)d_in[6];
    const float* bv = (const float*)d_in[7];
    const float* Wo = (const float*)d_in[8];
    const float* bo = (const float*)d_in[9];
    float* out = (float*)d_out;

    u16* wsu = (u16*)d_ws;
    // ws layout (u16 elems): [0 xbf 4.19M | 4.19M wq,wk,wv,wo 4x1.05M |
    //                         8.39M q,k,v 3x4.19M | 20.97M o 4.19M]  = 48 MB
    const size_t WBF = 4194304;
    const size_t QKV = 8388608;
    const size_t OWS = 20971520;
    const size_t QSZ = 4194304;

    prep_cvt<<<4096, 256, 0, stream>>>(x, Wq, Wk, Wv, Wo, wsu);
    qkv_gemm<<<768, 256, 0, stream>>>(wsu, wsu + WBF, bq, bk, bv, wsu + QKV);
    attn_kernel<<<512, 512, 0, stream>>>(wsu + QKV, wsu + QKV + QSZ,
                                         wsu + QKV + 2 * QSZ, ab, wsu + OWS);
    out_gemm<<<512, 256, 0, stream>>>(wsu + OWS, wsu + WBF + 3 * 1048576, bo, out);
}

// Round 6
// 503.763 us; speedup vs baseline: 1.2019x; 1.0035x over previous
//
#include <hip/hip_runtime.h>

typedef unsigned short u16;
typedef unsigned int u32;
using short8 = __attribute__((ext_vector_type(8))) short;
using f32x4  = __attribute__((ext_vector_type(4))) float;
using f32x16 = __attribute__((ext_vector_type(16))) float;

#define D_MODEL 1024
#define NHEAD 16
#define DKV 64
#define TSEQ 2048
#define BATCH 2
#define L2E 1.44269504f
#define CSHIFT 12.0f

// global -> LDS direct DMA, 16 B per lane. LDS dest must be wave-uniform
// base + lane*16 — our per-thread pointers satisfy that by construction.
#define GLOAD16(gp, lp)                                                      \
    __builtin_amdgcn_global_load_lds(                                        \
        (const __attribute__((address_space(1))) u32*)(gp),                  \
        (__attribute__((address_space(3))) u32*)(lp), 16, 0, 0)

__device__ __forceinline__ u16 f2bf(float f) {      // RNE
    union { float f; u32 i; } c; c.f = f;
    u32 x = c.i;
    return (u16)((x + 0x7FFFu + ((x >> 16) & 1u)) >> 16);
}
__device__ __forceinline__ u16 f2bf_fast(float f) { // round-half-up (P only)
    union { float f; u32 i; } c; c.f = f;
    return (u16)((c.i + 0x8000u) >> 16);
}

// ---------------------------------------------------------------------------
// Kernel 0: fp32 -> bf16 prep. (UNCHANGED)
// ---------------------------------------------------------------------------
__global__ __launch_bounds__(256) void prep_cvt(
    const float* __restrict__ x,  const float* __restrict__ Wq,
    const float* __restrict__ Wk, const float* __restrict__ Wv,
    const float* __restrict__ Wo, u16* __restrict__ dst)
{
    size_t e = ((size_t)blockIdx.x * 256 + threadIdx.x) * 8;
    const float* src; size_t off;
    if (e < 4194304u)      { src = x;  off = e; }
    else if (e < 5242880u) { src = Wq; off = e - 4194304u; }
    else if (e < 6291456u) { src = Wk; off = e - 5242880u; }
    else if (e < 7340032u) { src = Wv; off = e - 6291456u; }
    else                   { src = Wo; off = e - 7340032u; }
    float4 a = *(const float4*)(src + off);
    float4 b = *(const float4*)(src + off + 4);
    short8 v;
    v[0] = (short)f2bf(a.x); v[1] = (short)f2bf(a.y);
    v[2] = (short)f2bf(a.z); v[3] = (short)f2bf(a.w);
    v[4] = (short)f2bf(b.x); v[5] = (short)f2bf(b.y);
    v[6] = (short)f2bf(b.z); v[7] = (short)f2bf(b.w);
    *(short8*)(dst + e) = v;
}

// ---------------------------------------------------------------------------
// Kernel 1: fused QKV projection, m97 structure. (UNCHANGED)
// ---------------------------------------------------------------------------
__global__ __launch_bounds__(256) void qkv_gemm(
    const u16* __restrict__ xbf, const u16* __restrict__ wbf,
    const float* __restrict__ bq, const float* __restrict__ bk,
    const float* __restrict__ bv, u16* __restrict__ qkv)
{
    __shared__ __align__(16) u16 Alds[128 * 64];
    __shared__ __align__(16) u16 Blds[128 * 64];

    const int fid = blockIdx.x;
    const int xcd = fid & 7, ii = fid >> 3;       // ii in 0..95
    const int z = ii >> 5, r2 = ii & 31;
    const int nb = r2 & 7, mb = xcd * 4 + (r2 >> 3);
    const int n0 = nb * 128, m0 = mb * 128;
    const u16* W = wbf + (size_t)z * 1048576;
    const float* bias = (z == 0) ? bq : (z == 1) ? bk : bv;
    u16* out = qkv + (size_t)z * 4194304;

    const int t = threadIdx.x;
    const int wave = t >> 6, lane = t & 63, l15 = lane & 15, quad = lane >> 4;
    const int wm = (wave >> 1) * 64, wn = (wave & 1) * 64;

    f32x4 acc[4][4];
#pragma unroll
    for (int i = 0; i < 4; ++i)
#pragma unroll
        for (int j = 0; j < 4; ++j)
#pragma unroll
            for (int r = 0; r < 4; ++r) acc[i][j][r] = 0.f;

    const int rs = t >> 3, cs = (t & 7) * 8;
    const u16* ga = xbf + (size_t)(m0 + rs) * 1024 + cs;
    const u16* gb = W   + (size_t)(n0 + rs) * 1024 + cs;
    u16* la = &Alds[rs * 64 + cs];
    u16* lb = &Blds[rs * 64 + cs];

    for (int kt = 0; kt < 16; ++kt) {
        const int k0 = kt * 64;
#pragma unroll
        for (int c = 0; c < 4; ++c) {
            GLOAD16(ga + (size_t)(c * 32) * 1024 + k0, la + c * 32 * 64);
            GLOAD16(gb + (size_t)(c * 32) * 1024 + k0, lb + c * 32 * 64);
        }
        __syncthreads();
#pragma unroll
        for (int ki = 0; ki < 2; ++ki) {
            short8 af[4], bfr[4];
#pragma unroll
            for (int i = 0; i < 4; ++i)
                af[i] = *(const short8*)&Alds[(wm + i * 16 + l15) * 64 + ki * 32 + quad * 8];
#pragma unroll
            for (int j = 0; j < 4; ++j)
                bfr[j] = *(const short8*)&Blds[(wn + j * 16 + l15) * 64 + ki * 32 + quad * 8];
#pragma unroll
            for (int i = 0; i < 4; ++i)
#pragma unroll
                for (int j = 0; j < 4; ++j)
                    acc[i][j] = __builtin_amdgcn_mfma_f32_16x16x32_bf16(af[i], bfr[j], acc[i][j], 0, 0, 0);
        }
        __syncthreads();
    }

#pragma unroll
    for (int j = 0; j < 4; ++j) {
        int n = n0 + wn + j * 16 + l15;
        float bb = bias[n];
        int h = n >> 6, d = n & 63;
#pragma unroll
        for (int i = 0; i < 4; ++i)
#pragma unroll
            for (int r = 0; r < 4; ++r) {
                int m = m0 + wm + i * 16 + quad * 4 + r;
                int bidx = m >> 11, tt = m & 2047;
                out[(((size_t)(bidx * NHEAD + h)) * TSEQ + tt) * DKV + d] =
                    f2bf(acc[i][j][r] + bb);
            }
    }
}

// ---------------------------------------------------------------------------
// Kernel 2: flash attention, REWRITTEN with 32x32x16 MFMA fragments.
// Each wave owns 32 q-rows (block: 4 waves = 128 rows, one bh). Per 64-k tile
// per wave: 8 MFMA QK^T + 8 MFMA PV (vs 16 for 16 rows before) -> per-row
// instruction streams halve; per-CU wave-tile iterations 128 -> 64.
// Layouts (all conflict-checked):
//  - K [64][64] u16, staged by global_load_lds with pre-swizzled source
//    (R5-proven); frag read chunk = (dc*2+h5) ^ (l31&7) -> 8 bank-groups.
//  - Vt [2][64][72] u16 transposed (R3-proven stride-72): logical u16 index
//    k with phys chunk = (k>>3) ^ (d>>3); packed-u32 staging verbatim.
//  - Plds [wave][32][72]: wave-private -> NO barrier between P-write and PV.
// Schedule = R5's: QK^T -> bar#1 -> prefetch(K gload, V->regs, bias(kt+1))
// -> softmax(bz) -> PV -> V ds_write -> bar#2 (drain covered by compute).
// C/D layout (m74/m101): col=lane&31, row=(reg&3)+8*(reg>>2)+4*(lane>>5).
// Fixed-shift softmax (exact: constant shift cancels). ~205 VGPR -> 8 w/CU.
// ---------------------------------------------------------------------------
__global__ __launch_bounds__(256, 2) void attn_kernel(
    const u16* __restrict__ qws, const u16* __restrict__ kws, const u16* __restrict__ vws,
    const float* __restrict__ bias, u16* __restrict__ ows)
{
    __shared__ __align__(16) u16 Klds[64 * 64];
    __shared__ __align__(16) u16 Vt[2][64 * 72];
    __shared__ __align__(16) u16 Plds[4 * 32 * 72];

    const int fid = blockIdx.x;
    const int xcd = fid & 7, ii = fid >> 3;        // ii in 0..63
    const int bh = xcd * 4 + (ii >> 4);            // 0..31, 4 bh per XCD
    const int qt = ii & 15;
    const int h = bh & 15;

    const int t = threadIdx.x;
    const int wave = t >> 6, lane = t & 63, l31 = lane & 31, h5 = lane >> 5;
    const int qw = qt * 128 + wave * 32;           // wave's q-row base
    const size_t bhoff = (size_t)bh * TSEQ * DKV;

    // Q A-fragments, loop-invariant: qa[dc] = Q[qw+l31][dc*16 + h5*8 ..+7]
    short8 qa[4];
    {
        const u16* qp = qws + bhoff + (size_t)(qw + l31) * DKV + h5 * 8;
#pragma unroll
        for (int dc = 0; dc < 4; ++dc)
            qa[dc] = *(const short8*)(qp + dc * 16);
    }

    float l_run[16];
#pragma unroll
    for (int r = 0; r < 16; ++r) l_run[r] = 0.f;
    f32x16 oacc[2];
#pragma unroll
    for (int dn = 0; dn < 2; ++dn)
#pragma unroll
        for (int r = 0; r < 16; ++r) oacc[dn][r] = 0.f;

    const float* bias_h = bias + ((size_t)h * TSEQ + qw) * TSEQ;
    const int a8 = t & 7, c8 = a8 * 8, rp = t >> 3;
    const int vbk = rp >> 2, vkcl = (2 * rp) & 7;
    const int wbase = wave * (32 * 72);

    // staging pointers. K source pre-swizzled per row (lds[row] holds chunk
    // c at phys c ^ (row&7)); LDS dest byte = 16*t (lane-linear, required).
    const u16* kpbase = kws + bhoff + (size_t)rp * DKV + ((a8 ^ (rp & 7)) * 8);
    const u16* vpbase = vws + bhoff + (size_t)(2 * rp) * DKV + c8;
    u16* kl = &Klds[rp * 64 + c8];

    // --- prologue: stage K[0], V[0]; bias tile 0 -> bz ---
    GLOAD16(kpbase, kl);
    GLOAD16(kpbase + 32 * DKV, kl + 32 * 64);
    {
        short8 v0 = *(const short8*)vpbase;
        short8 v1 = *(const short8*)(vpbase + DKV);
        u16* vtb = &Vt[0][0];
#pragma unroll
        for (int j = 0; j < 8; ++j) {
            int d = c8 + j;
            u32 val = ((u32)(u16)v0[j]) | (((u32)(u16)v1[j]) << 16);
            *(u32*)&vtb[d * 72 + ((vbk ^ a8) * 8) + vkcl] = val;
        }
    }
    float bz[32];
#pragma unroll
    for (int kn = 0; kn < 2; ++kn)
#pragma unroll
        for (int r = 0; r < 16; ++r)
            bz[kn * 16 + r] =
                bias_h[(size_t)((r & 3) + 8 * (r >> 2) + 4 * h5) * TSEQ + kn * 32 + l31];
    __syncthreads();

    for (int kt = 0; kt < TSEQ / 64; ++kt) {
        const int cur = kt & 1;

        // [A] S = Q K^T : s[kn] covers k-cols kn*32..+31; accumulate over d
        f32x16 s[2];
#pragma unroll
        for (int kn = 0; kn < 2; ++kn)
#pragma unroll
            for (int r = 0; r < 16; ++r) s[kn][r] = 0.f;
#pragma unroll
        for (int dc = 0; dc < 4; ++dc) {
#pragma unroll
            for (int kn = 0; kn < 2; ++kn) {
                short8 kb = *(const short8*)
                    &Klds[(kn * 32 + l31) * 64 + (((dc * 2 + h5) ^ (l31 & 7)) * 8)];
                s[kn] = __builtin_amdgcn_mfma_f32_32x32x16_bf16(qa[dc], kb, s[kn], 0, 0, 0);
            }
        }

        // [B] barrier #1: all QK^T reads done; Klds free (nothing in flight)
        __syncthreads();

        // [C] prefetch tile kt+1 (clamped; redundant last re-stage harmless):
        // K -> LDS direct, V -> regs, bias -> bzn. Drained at [G] under D-F.
        const int ktn = (kt < 31) ? kt + 1 : kt;
        const size_t koff = (size_t)ktn * 64 * DKV;
        GLOAD16(kpbase + koff, kl);
        GLOAD16(kpbase + koff + 32 * DKV, kl + 32 * 64);
        short8 v0n = *(const short8*)(vpbase + koff);
        short8 v1n = *(const short8*)(vpbase + koff + DKV);
        float bzn[32];
#pragma unroll
        for (int kn = 0; kn < 2; ++kn)
#pragma unroll
            for (int r = 0; r < 16; ++r)
                bzn[kn * 16 + r] =
                    bias_h[(size_t)((r & 3) + 8 * (r >> 2) + 4 * h5) * TSEQ +
                           ktn * 64 + kn * 32 + l31];

        // [D] p = exp2(s/8*log2e + bias*log2e - C*log2e); l += p; P -> LDS
#pragma unroll
        for (int kn = 0; kn < 2; ++kn)
#pragma unroll
            for (int r = 0; r < 16; ++r) {
                float arg = fmaf(s[kn][r], 0.125f * L2E,
                                 fmaf(bz[kn * 16 + r], L2E, -CSHIFT * L2E));
                float p = exp2f(arg);
                l_run[r] += p;
                int row = (r & 3) + 8 * (r >> 2) + 4 * h5;
                Plds[wbase + row * 72 + kn * 32 + l31] = f2bf_fast(p);
            }

        // [E] PV: O += P V (own P rows: same-wave DS ordering, no barrier)
#pragma unroll
        for (int kc = 0; kc < 4; ++kc) {
            short8 pa = *(const short8*)&Plds[wbase + l31 * 72 + kc * 16 + h5 * 8];
#pragma unroll
            for (int dn = 0; dn < 2; ++dn) {
                int d = dn * 32 + l31;
                short8 vb = *(const short8*)
                    &Vt[cur][d * 72 + (((kc * 2 + h5) ^ ((d >> 3) & 7)) * 8)];
                oacc[dn] = __builtin_amdgcn_mfma_f32_32x32x16_bf16(pa, vb, oacc[dn], 0, 0, 0);
            }
        }

        // [F] V ds_write for tile kt+1 into Vt[cur^1]; roll bias regs
        {
            u16* vtb = &Vt[cur ^ 1][0];
#pragma unroll
            for (int j = 0; j < 8; ++j) {
                int d = c8 + j;
                u32 val = ((u32)(u16)v0n[j]) | (((u32)(u16)v1n[j]) << 16);
                *(u32*)&vtb[d * 72 + ((vbk ^ a8) * 8) + vkcl] = val;
            }
        }
#pragma unroll
        for (int i = 0; i < 32; ++i) bz[i] = bzn[i];

        // [G] barrier #2: drains K global_load_lds + V writes + bias loads
        __syncthreads();
    }

    // epilogue: l reduction over the 32 k-lanes (q differs across lane>>5:
    // masks up to 16 only), then normalized O store.
#pragma unroll
    for (int r = 0; r < 16; ++r) {
        float v = l_run[r];
        v += __shfl_xor(v, 1);
        v += __shfl_xor(v, 2);
        v += __shfl_xor(v, 4);
        v += __shfl_xor(v, 8);
        v += __shfl_xor(v, 16);
        float inv = 1.f / v;
        int row = qw + (r & 3) + 8 * (r >> 2) + 4 * h5;
#pragma unroll
        for (int dn = 0; dn < 2; ++dn)
            ows[bhoff + (size_t)row * DKV + dn * 32 + l31] = f2bf(oacc[dn][r] * inv);
    }
}

// ---------------------------------------------------------------------------
// Kernel 3: output projection, 128x64 tiles -> grid 512 = 2 blocks/CU.
// (UNCHANGED)
// ---------------------------------------------------------------------------
__global__ __launch_bounds__(256) void out_gemm(
    const u16* __restrict__ ows, const u16* __restrict__ wobf,
    const float* __restrict__ bo, float* __restrict__ out)
{
    __shared__ __align__(16) u16 Alds[128 * 64];
    __shared__ __align__(16) u16 Blds[64 * 64];

    const int fid = blockIdx.x;
    const int xcd = fid & 7, ii = fid >> 3;     // ii in 0..63
    const int nb = ii & 15, mb = xcd * 4 + (ii >> 4);
    const int n0 = nb * 64, m0 = mb * 128;

    const int t = threadIdx.x;
    const int wave = t >> 6, lane = t & 63, l15 = lane & 15, quad = lane >> 4;
    const int wm = (wave >> 1) * 64, wn = (wave & 1) * 32;   // wave tile 64x32

    f32x4 acc[4][2];
#pragma unroll
    for (int i = 0; i < 4; ++i)
#pragma unroll
        for (int j = 0; j < 2; ++j)
#pragma unroll
            for (int r = 0; r < 4; ++r) acc[i][j][r] = 0.f;

    const int rs = t >> 3, cs = (t & 7) * 8;
    const int bidx = m0 >> 11, tt0 = m0 & 2047;    // 128-row tile never crosses batch
    const u16* gaBase = ows + (((size_t)(bidx * NHEAD)) * TSEQ + tt0 + rs) * DKV + cs;
    const u16* gb = wobf + (size_t)(n0 + rs) * 1024 + cs;
    u16* la = &Alds[rs * 64 + cs];
    u16* lb = &Blds[rs * 64 + cs];

    for (int kt = 0; kt < 16; ++kt) {
        const int k0 = kt * 64;
#pragma unroll
        for (int c = 0; c < 4; ++c)
            GLOAD16(gaBase + ((size_t)kt * TSEQ + c * 32) * DKV, la + c * 32 * 64);
#pragma unroll
        for (int c = 0; c < 2; ++c)
            GLOAD16(gb + (size_t)(c * 32) * 1024 + k0, lb + c * 32 * 64);
        __syncthreads();
#pragma unroll
        for (int ki = 0; ki < 2; ++ki) {
            short8 af[4], bfr[2];
#pragma unroll
            for (int i = 0; i < 4; ++i)
                af[i] = *(const short8*)&Alds[(wm + i * 16 + l15) * 64 + ki * 32 + quad * 8];
#pragma unroll
            for (int j = 0; j < 2; ++j)
                bfr[j] = *(const short8*)&Blds[(wn + j * 16 + l15) * 64 + ki * 32 + quad * 8];
#pragma unroll
            for (int i = 0; i < 4; ++i)
#pragma unroll
                for (int j = 0; j < 2; ++j)
                    acc[i][j] = __builtin_amdgcn_mfma_f32_16x16x32_bf16(af[i], bfr[j], acc[i][j], 0, 0, 0);
        }
        __syncthreads();
    }

#pragma unroll
    for (int j = 0; j < 2; ++j) {
        int n = n0 + wn + j * 16 + l15;
        float bb = bo[n];
#pragma unroll
        for (int i = 0; i < 4; ++i)
#pragma unroll
            for (int r = 0; r < 4; ++r) {
                int m = m0 + wm + i * 16 + quad * 4 + r;
                out[(size_t)m * 1024 + n] = acc[i][j][r] + bb;
            }
    }
}

extern "C" void kernel_launch(void* const* d_in, const int* in_sizes, int n_in,
                              void* d_out, int out_size, void* d_ws, size_t ws_size,
                              hipStream_t stream)
{
    const float* x  = (const float*)d_in[0];
    const float* ab = (const float*)d_in[1];
    const float* Wq = (const float*)d_in[2];
    const float* bq = (const float*)d_in[3];
    const float* Wk = (const float*)d_in[4];
    const float* bk = (const float*)d_in[5];
    const float* Wv = (const float*)d_in[6];
    const float* bv = (const float*)d_in[7];
    const float* Wo = (const float*)d_in[8];
    const float* bo = (const float*)d_in[9];
    float* out = (float*)d_out;

    u16* wsu = (u16*)d_ws;
    // ws layout (u16 elems): [0 xbf 4.19M | 4.19M wq,wk,wv,wo 4x1.05M |
    //                         8.39M q,k,v 3x4.19M | 20.97M o 4.19M]  = 48 MB
    const size_t WBF = 4194304;
    const size_t QKV = 8388608;
    const size_t OWS = 20971520;
    const size_t QSZ = 4194304;

    prep_cvt<<<4096, 256, 0, stream>>>(x, Wq, Wk, Wv, Wo, wsu);
    qkv_gemm<<<768, 256, 0, stream>>>(wsu, wsu + WBF, bq, bk, bv, wsu + QKV);
    attn_kernel<<<512, 256, 0, stream>>>(wsu + QKV, wsu + QKV + QSZ,
                                         wsu + QKV + 2 * QSZ, ab, wsu + OWS);
    out_gemm<<<512, 256, 0, stream>>>(wsu + OWS, wsu + WBF + 3 * 1048576, bo, out);
}